// Round 6
// baseline (122.025 us; speedup 1.0000x reference)
//
#include <hip/hip_runtime.h>

// MRConv1d: B=4, N=10000, C=128, K=16, OUT=128
// out[b,n,o] = relu( sum_c2 feat[b,n,c2]*W[o,c2] + bias[o] )
// feat[b,n,2c]   = x[b,n,c]
// feat[b,n,2c+1] = max_k( x[b, e0[b,n,k], c] - x[b, e1[b,n,k], c] )
//
// Ledger: R4 nt-hints null. R6 batch-per-launch regressed (confounded).
// R7 measurement: hot gather = 11 us (L2-BW floor); cold premium ~25-30 us.
// R8 cross-kernel L2 pre-warm null => L2 invalidated at kernel boundaries.
// R9 (this round): batch <- PHYSICAL XCD. Read HW_REG_XCC_ID (wave-uniform,
//   values 0..7 on MI355X) and take node-tiles of batch (xcc&3) from a
//   per-batch atomic counter. Guarantees each XCD's L2 serves exactly one
//   2.56 MB slice regardless of the (undefined) block->XCD mapping -- the
//   static bid&7 swizzle is the prime suspect for the sustained L2 thrash
//   (4 slices = 10.24 MB working set per 4 MiB L2). Spill path keeps
//   correctness under arbitrary mappings. Gather body = the proven R4 one.

#define Bn 4
#define Nn 10000
#define Cn 128
#define Kn 16
#define OUTn 128
#define Mn 16           // nodes per tile
#define NT (Nn / Mn)    // 625 tiles per batch
#define FPAD 8          // sfeat row pad (row = 264 ushorts = 528 B)

typedef __attribute__((ext_vector_type(8))) short short8;
typedef __attribute__((ext_vector_type(4))) float floatx4;

__device__ __forceinline__ unsigned short f2bf(float f) {
    union { float f; unsigned u; } v; v.f = f;
    unsigned r = v.u + 0x7fffu + ((v.u >> 16) & 1u);   // RNE
    return (unsigned short)(r >> 16);
}
__device__ __forceinline__ float bf2f(unsigned short h) {
    union { unsigned u; float f; } v; v.u = ((unsigned)h) << 16;
    return v.f;
}

// Fused prep: blocks 0..15 pack W (block 0 also zeroes the work counters),
// blocks 16..2515 convert x fp32 -> bf16 (8 floats/thread, linear).
__global__ __launch_bounds__(256) void prep_kernel(const float* __restrict__ x,
                                                   const float* __restrict__ W,
                                                   unsigned short* __restrict__ xh,
                                                   unsigned short* __restrict__ Wb,
                                                   int* __restrict__ cnt) {
    int bi = blockIdx.x;
    int t = threadIdx.x;
    if (bi < 16) {
        if (bi == 0 && t < 8) cnt[t] = 0;       // zero work counters each call
        int tid = bi * 256 + t;                 // 0..4095
        int lane = tid & 63;
        int step = (tid >> 6) & 7;
        int tile = tid >> 9;
        int o = tile * 16 + (lane & 15);
        int quad = lane >> 4;
        unsigned short v[8];
#pragma unroll
        for (int j = 0; j < 8; ++j) {
            int c2 = step * 32 + quad * 8 + j;
            v[j] = f2bf(W[o * (2 * Cn) + c2]);
        }
        uint4 pk;
        pk.x = (unsigned)v[0] | ((unsigned)v[1] << 16);
        pk.y = (unsigned)v[2] | ((unsigned)v[3] << 16);
        pk.z = (unsigned)v[4] | ((unsigned)v[5] << 16);
        pk.w = (unsigned)v[6] | ((unsigned)v[7] << 16);
        *(uint4*)(Wb + (size_t)tid * 8) = pk;
        return;
    }
    int i = (bi - 16) * 256 + t;                // 0..639999
    const float4* x4 = (const float4*)x;
    float4 a = x4[2 * i];
    float4 c = x4[2 * i + 1];
    uint4 pk;
    pk.x = (unsigned)f2bf(a.x) | ((unsigned)f2bf(a.y) << 16);
    pk.y = (unsigned)f2bf(a.z) | ((unsigned)f2bf(a.w) << 16);
    pk.z = (unsigned)f2bf(c.x) | ((unsigned)f2bf(c.y) << 16);
    pk.w = (unsigned)f2bf(c.z) | ((unsigned)f2bf(c.w) << 16);
    *(uint4*)(xh + 8 * (size_t)i) = pk;
}

__global__ __launch_bounds__(256) void mrconv_kernel(
    const unsigned short* __restrict__ xh, const int* __restrict__ edge,
    const unsigned short* __restrict__ Wb, const float* __restrict__ bias,
    float* __restrict__ out, int* __restrict__ cnt)
{
    __shared__ unsigned short sfeat[Mn][2 * Cn + FPAD];  // bf16 feature tile
    __shared__ int sidx[2][Mn][Kn];
    __shared__ int s_hdr[2];

    const int t = threadIdx.x;

    // Bind batch to the PHYSICAL XCD: this XCD's L2 then only ever serves one
    // 2.56 MB batch slice. Tile comes from a per-batch atomic work queue;
    // spill path (probe other batches) keeps every tile processed exactly
    // once under any block->XCD mapping.
    if (t == 0) {
        unsigned xcc = 0;
        asm volatile("s_getreg_b32 %0, hwreg(HW_REG_XCC_ID)" : "=s"(xcc));
        int b = (int)(xcc & 3u);
        int tile = atomicAdd(&cnt[b], 1);
        int tries = 0;
        while (tile >= NT && tries < 3) {
            b = (b + 1) & 3;
            tile = atomicAdd(&cnt[b], 1);
            ++tries;
        }
        if (tile >= NT) b = -1;
        s_hdr[0] = b;
        s_hdr[1] = tile;
    }
    __syncthreads();
    const int b = s_hdr[0];
    const int nb = s_hdr[1];
    if (b < 0) return;                 // all work handed out

    const int n0 = nb * Mn;
    const int gbase = b * Nn + n0;
    const int wv = t >> 6;      // wave 0..3
    const int lane = t & 63;

    // stage edge indices for the tile's 16 nodes: 2*16*16 = 512 ints.
    for (int i = t; i < 2 * Mn * Kn; i += 256) {
        int s = i >> 8;
        int m = (i >> 4) & 15;
        int k = i & 15;
        sidx[s][m][k] = __builtin_nontemporal_load(
            &edge[s * (Bn * Nn * Kn) + (gbase + m) * Kn + k]);
    }
    __syncthreads();

    const unsigned short* xbb = xh + (size_t)b * Nn * Cn;

    // phase 1: gather + max-relative in bf16 (proven R4 body).
    // Quarter-wave per row: 16 lanes x short8 (16 B) = 256 B row; 16 loads
    // in flight per lane.
    {
        const int q = lane >> 4;          // quarter 0..3
        const int l16 = lane & 15;
        const int m = wv * 4 + q;         // node 0..15
        const int ch = l16 * 8;           // 8 channels per lane
        const short8 xs = *(const short8*)(xbb + (n0 + m) * Cn + ch);
        float r[8];
#pragma unroll
        for (int e = 0; e < 8; ++e) r[e] = -3.402823466e+38f;
#pragma unroll
        for (int kc = 0; kc < 2; ++kc) {
            short8 vj[8], vi[8];
#pragma unroll
            for (int u = 0; u < 8; ++u) {
                const int jj = sidx[0][m][kc * 8 + u];
                const int ii = sidx[1][m][kc * 8 + u];
                vj[u] = *(const short8*)(xbb + jj * Cn + ch);
                vi[u] = *(const short8*)(xbb + ii * Cn + ch);
            }
#pragma unroll
            for (int u = 0; u < 8; ++u) {
#pragma unroll
                for (int e = 0; e < 8; ++e) {
                    r[e] = fmaxf(r[e], bf2f((unsigned short)vj[u][e]) -
                                       bf2f((unsigned short)vi[u][e]));
                }
            }
        }
        // interleaved bf16 row: {x_c, rel_c} pairs; lane covers c in [ch, ch+8)
        uint4 pk0, pk1;
        pk0.x = (unsigned short)xs[0] | ((unsigned)f2bf(r[0]) << 16);
        pk0.y = (unsigned short)xs[1] | ((unsigned)f2bf(r[1]) << 16);
        pk0.z = (unsigned short)xs[2] | ((unsigned)f2bf(r[2]) << 16);
        pk0.w = (unsigned short)xs[3] | ((unsigned)f2bf(r[3]) << 16);
        pk1.x = (unsigned short)xs[4] | ((unsigned)f2bf(r[4]) << 16);
        pk1.y = (unsigned short)xs[5] | ((unsigned)f2bf(r[5]) << 16);
        pk1.z = (unsigned short)xs[6] | ((unsigned)f2bf(r[6]) << 16);
        pk1.w = (unsigned short)xs[7] | ((unsigned)f2bf(r[7]) << 16);
        *(uint4*)&sfeat[m][2 * ch] = pk0;
        *(uint4*)&sfeat[m][2 * ch + 8] = pk1;
    }
    __syncthreads();

    // phase 2: out_tile[16 nodes][128] = feat[16][256] @ Wt[256][128] via MFMA.
    const int m16 = lane & 15;
    const int quad = lane >> 4;
    floatx4 acc0 = {0.f, 0.f, 0.f, 0.f};
    floatx4 acc1 = {0.f, 0.f, 0.f, 0.f};
    const short8* wb8 = (const short8*)Wb;
    const int tile0 = 2 * wv, tile1 = 2 * wv + 1;
#pragma unroll
    for (int step = 0; step < 8; ++step) {
        short8 a = *(const short8*)&sfeat[m16][step * 32 + quad * 8];
        short8 b0 = wb8[(tile0 * 8 + step) * 64 + lane];
        short8 b1 = wb8[(tile1 * 8 + step) * 64 + lane];
        acc0 = __builtin_amdgcn_mfma_f32_16x16x32_bf16(a, b0, acc0, 0, 0, 0);
        acc1 = __builtin_amdgcn_mfma_f32_16x16x32_bf16(a, b1, acc1, 0, 0, 0);
    }
    // C/D layout: col = lane&15, row = quad*4 + reg
    const int o0 = tile0 * 16 + m16;
    const int o1 = tile1 * 16 + m16;
    const float bb0 = bias[o0], bb1 = bias[o1];
#pragma unroll
    for (int r = 0; r < 4; ++r) {
        int g = gbase + quad * 4 + r;
        __builtin_nontemporal_store(fmaxf(acc0[r] + bb0, 0.f), &out[g * OUTn + o0]);
        __builtin_nontemporal_store(fmaxf(acc1[r] + bb1, 0.f), &out[g * OUTn + o1]);
    }
}

extern "C" void kernel_launch(void* const* d_in, const int* in_sizes, int n_in,
                              void* d_out, int out_size, void* d_ws, size_t ws_size,
                              hipStream_t stream) {
    const float* x = (const float*)d_in[0];
    const int* edge = (const int*)d_in[1];
    const float* W = (const float*)d_in[2];
    const float* bias = (const float*)d_in[3];
    float* out = (float*)d_out;

    unsigned short* Wb = (unsigned short*)d_ws;                      // 64 KB
    unsigned short* xh = (unsigned short*)((char*)d_ws + 65536);     // 10.24 MB
    int* cnt = (int*)((char*)d_ws + 65536 + 10240000);               // 32 B

    prep_kernel<<<2516, 256, 0, stream>>>(x, W, xh, Wb, cnt);
    mrconv_kernel<<<2560, 256, 0, stream>>>(xh, edge, Wb, bias, out, cnt);
}

// Round 7
// 104.453 us; speedup vs baseline: 1.1682x; 1.1682x over previous
//
#include <hip/hip_runtime.h>

// MRConv1d: B=4, N=10000, C=128, K=16, OUT=128
// out[b,n,o] = relu( sum_c2 feat[b,n,c2]*W[o,c2] + bias[o] )
// feat[b,n,2c]   = x[b,n,c]
// feat[b,n,2c+1] = max_k( x[b, e0[b,n,k], c] - x[b, e1[b,n,k], c] )
//
// Ledger: R4 nt-hints null. R6 batch-per-launch regressed. R8 L2 pre-warm
//   null (L2 invalidated at kernel boundaries). R9 XCD atomic queue regressed
//   (atomic serialization) BUT delivered counters: FETCH=13 MB (compulsory
//   only -- gather never misses to HBM; all cache-locality theories dead),
//   MfmaUtil 2 / VALUBusy 22 / Occ 44 (latency-bound), VGPR_Count=44 (!).
// R10 (this round): the 44-VGPR allocation is the bottleneck. launch_bounds
//   with no wave floor made the allocator sink the 16-deep gather burst to
//   ~4-8 real outstanding loads/lane; every wave eats L2/L3 latency ~4x per
//   tile. Fix: __launch_bounds__(256,3) (~170 VGPR budget) + flatten the
//   k-chunking so all 32 gather loads (vj[16]+vi[16] = 128 data VGPRs) issue
//   as one burst before any consume. Structure otherwise = proven R4 102 us
//   config (static swizzle, sidx LDS staging, fused prep, nt out/edge).

#define Bn 4
#define Nn 10000
#define Cn 128
#define Kn 16
#define OUTn 128
#define Mn 16           // nodes per block
#define FPAD 8          // sfeat row pad (row = 264 ushorts = 528 B)

typedef __attribute__((ext_vector_type(8))) short short8;
typedef __attribute__((ext_vector_type(4))) float floatx4;

__device__ __forceinline__ unsigned short f2bf(float f) {
    union { float f; unsigned u; } v; v.f = f;
    unsigned r = v.u + 0x7fffu + ((v.u >> 16) & 1u);   // RNE
    return (unsigned short)(r >> 16);
}
__device__ __forceinline__ float bf2f(unsigned short h) {
    union { unsigned u; float f; } v; v.u = ((unsigned)h) << 16;
    return v.f;
}

// Fused prep: blocks 0..15 pack W, blocks 16..2515 convert x (8 floats/thread).
__global__ __launch_bounds__(256) void prep_kernel(const float* __restrict__ x,
                                                   const float* __restrict__ W,
                                                   unsigned short* __restrict__ xh,
                                                   unsigned short* __restrict__ Wb) {
    int bi = blockIdx.x;
    int t = threadIdx.x;
    if (bi < 16) {
        int tid = bi * 256 + t;                 // 0..4095
        int lane = tid & 63;
        int step = (tid >> 6) & 7;
        int tile = tid >> 9;
        int o = tile * 16 + (lane & 15);
        int quad = lane >> 4;
        unsigned short v[8];
#pragma unroll
        for (int j = 0; j < 8; ++j) {
            int c2 = step * 32 + quad * 8 + j;
            v[j] = f2bf(W[o * (2 * Cn) + c2]);
        }
        uint4 pk;
        pk.x = (unsigned)v[0] | ((unsigned)v[1] << 16);
        pk.y = (unsigned)v[2] | ((unsigned)v[3] << 16);
        pk.z = (unsigned)v[4] | ((unsigned)v[5] << 16);
        pk.w = (unsigned)v[6] | ((unsigned)v[7] << 16);
        *(uint4*)(Wb + (size_t)tid * 8) = pk;
        return;
    }
    int i = (bi - 16) * 256 + t;                // 0..639999
    const float4* x4 = (const float4*)x;
    float4 a = x4[2 * i];
    float4 c = x4[2 * i + 1];
    uint4 pk;
    pk.x = (unsigned)f2bf(a.x) | ((unsigned)f2bf(a.y) << 16);
    pk.y = (unsigned)f2bf(a.z) | ((unsigned)f2bf(a.w) << 16);
    pk.z = (unsigned)f2bf(c.x) | ((unsigned)f2bf(c.y) << 16);
    pk.w = (unsigned)f2bf(c.z) | ((unsigned)f2bf(c.w) << 16);
    *(uint4*)(xh + 8 * (size_t)i) = pk;
}

// launch_bounds(256, 3): min 3 waves/SIMD -> ~170 VGPR budget. The gather
// burst below NEEDS ~156 VGPRs live; at the default allocation (44) the
// compiler serializes the loads and the kernel is latency-bound (R9 PMC).
__global__ __launch_bounds__(256, 3) void mrconv_kernel(
    const unsigned short* __restrict__ xh, const int* __restrict__ edge,
    const unsigned short* __restrict__ Wb, const float* __restrict__ bias,
    float* __restrict__ out)
{
    __shared__ unsigned short sfeat[Mn][2 * Cn + FPAD];  // bf16 feature tile
    __shared__ int sidx[2][Mn][Kn];

    int bi = blockIdx.x;
    int slot = bi & 7;
    int b = slot & 3;
    int nb = (bi >> 3) * 2 + (slot >> 2);
    if (nb >= Nn / Mn) return;
    const int n0 = nb * Mn;
    const int gbase = b * Nn + n0;

    const int t = threadIdx.x;
    const int wv = t >> 6;      // wave 0..3
    const int lane = t & 63;

    // stage edge indices for the block's 16 nodes: 2*16*16 = 512 ints.
    for (int i = t; i < 2 * Mn * Kn; i += 256) {
        int s = i >> 8;
        int m = (i >> 4) & 15;
        int k = i & 15;
        sidx[s][m][k] = __builtin_nontemporal_load(
            &edge[s * (Bn * Nn * Kn) + (gbase + m) * Kn + k]);
    }
    __syncthreads();

    const unsigned short* xbb = xh + (size_t)b * Nn * Cn;

    // phase 1: gather + max-relative in bf16.
    // Quarter-wave per row: 16 lanes x short8 (16 B) = 256 B row. ALL 32
    // loads issue as one burst (vj+vi = 128 data VGPRs) before any consume:
    // one latency exposure per tile instead of ~4.
    {
        const int q = lane >> 4;          // quarter 0..3
        const int l16 = lane & 15;
        const int m = wv * 4 + q;         // node 0..15
        const int ch = l16 * 8;           // 8 channels per lane
        const short8 xs = *(const short8*)(xbb + (n0 + m) * Cn + ch);
        short8 vj[16], vi[16];
#pragma unroll
        for (int u = 0; u < 16; ++u) {
            const int jj = sidx[0][m][u];
            const int ii = sidx[1][m][u];
            vj[u] = *(const short8*)(xbb + jj * Cn + ch);
            vi[u] = *(const short8*)(xbb + ii * Cn + ch);
        }
        float r[8];
#pragma unroll
        for (int e = 0; e < 8; ++e) r[e] = -3.402823466e+38f;
#pragma unroll
        for (int u = 0; u < 16; ++u) {
#pragma unroll
            for (int e = 0; e < 8; ++e) {
                r[e] = fmaxf(r[e], bf2f((unsigned short)vj[u][e]) -
                                   bf2f((unsigned short)vi[u][e]));
            }
        }
        // interleaved bf16 row: {x_c, rel_c} pairs; lane covers c in [ch, ch+8)
        uint4 pk0, pk1;
        pk0.x = (unsigned short)xs[0] | ((unsigned)f2bf(r[0]) << 16);
        pk0.y = (unsigned short)xs[1] | ((unsigned)f2bf(r[1]) << 16);
        pk0.z = (unsigned short)xs[2] | ((unsigned)f2bf(r[2]) << 16);
        pk0.w = (unsigned short)xs[3] | ((unsigned)f2bf(r[3]) << 16);
        pk1.x = (unsigned short)xs[4] | ((unsigned)f2bf(r[4]) << 16);
        pk1.y = (unsigned short)xs[5] | ((unsigned)f2bf(r[5]) << 16);
        pk1.z = (unsigned short)xs[6] | ((unsigned)f2bf(r[6]) << 16);
        pk1.w = (unsigned short)xs[7] | ((unsigned)f2bf(r[7]) << 16);
        *(uint4*)&sfeat[m][2 * ch] = pk0;
        *(uint4*)&sfeat[m][2 * ch + 8] = pk1;
    }
    __syncthreads();

    // phase 2: out_tile[16 nodes][128] = feat[16][256] @ Wt[256][128] via MFMA.
    const int m16 = lane & 15;
    const int quad = lane >> 4;
    floatx4 acc0 = {0.f, 0.f, 0.f, 0.f};
    floatx4 acc1 = {0.f, 0.f, 0.f, 0.f};
    const short8* wb8 = (const short8*)Wb;
    const int tile0 = 2 * wv, tile1 = 2 * wv + 1;
#pragma unroll
    for (int step = 0; step < 8; ++step) {
        short8 a = *(const short8*)&sfeat[m16][step * 32 + quad * 8];
        short8 b0 = wb8[(tile0 * 8 + step) * 64 + lane];
        short8 b1 = wb8[(tile1 * 8 + step) * 64 + lane];
        acc0 = __builtin_amdgcn_mfma_f32_16x16x32_bf16(a, b0, acc0, 0, 0, 0);
        acc1 = __builtin_amdgcn_mfma_f32_16x16x32_bf16(a, b1, acc1, 0, 0, 0);
    }
    // C/D layout: col = lane&15, row = quad*4 + reg
    const int o0 = tile0 * 16 + m16;
    const int o1 = tile1 * 16 + m16;
    const float bb0 = bias[o0], bb1 = bias[o1];
#pragma unroll
    for (int r = 0; r < 4; ++r) {
        int g = gbase + quad * 4 + r;
        __builtin_nontemporal_store(fmaxf(acc0[r] + bb0, 0.f), &out[g * OUTn + o0]);
        __builtin_nontemporal_store(fmaxf(acc1[r] + bb1, 0.f), &out[g * OUTn + o1]);
    }
}

extern "C" void kernel_launch(void* const* d_in, const int* in_sizes, int n_in,
                              void* d_out, int out_size, void* d_ws, size_t ws_size,
                              hipStream_t stream) {
    const float* x = (const float*)d_in[0];
    const int* edge = (const int*)d_in[1];
    const float* W = (const float*)d_in[2];
    const float* bias = (const float*)d_in[3];
    float* out = (float*)d_out;

    unsigned short* Wb = (unsigned short*)d_ws;                  // 64 KB
    unsigned short* xh = (unsigned short*)((char*)d_ws + 65536); // 10.24 MB

    prep_kernel<<<2516, 256, 0, stream>>>(x, W, xh, Wb);
    mrconv_kernel<<<2560, 256, 0, stream>>>(xh, edge, Wb, bias, out);
}